// Round 20
// baseline (248.406 us; speedup 1.0000x reference)
//
#include <hip/hip_runtime.h>
#include <hip/hip_bf16.h>
#include <cstddef>

// R20 = R19 (fp16 single-term, granule regions, static period-6 unroll,
// 247us) reshaped 12 -> 16 waves (4/SIMD), NO orphan:
//   L0: w0-3  NT=4,3,3,3 (T0=0,4,7,10; w3 also stages x)
//   L1: w4-9  NT=3,2,2,2,2,2 (T0=0,3,5,7,9,11)
//   L2: w10-15 same tiling
// Tile 12 (units 48-51, valid 48-49) covered by the generic n<50 guard.
// Schedule/numerics byte-identical to R19:
//   L0@it: read H0[p&1], write h0 -> H0[(p+1)&1]; x(it+1) -> H0[(p+1)&1].g0
//   L1@it (t=it-1): x-side H0[p&1] (+1g), h-side H1[(p+1)%3], write H1[(p+2)%3]
//   L2@it (t=it-2): x-side H1[(p+1)%3], h-side H2[(p+1)&1], write H2[p&1]
// fp16 weights/acts, pre-scaled gates, 8-trans fused update, 1 s_barrier/iter.

#define T_STEPS 256
#define NGRP    43           // 43 * 6 = 258 iterations
#define BTOT    4096
#define NTHR    1024
#define GS      128
#define BUFR    1152

typedef __attribute__((ext_vector_type(8))) _Float16 half8;
typedef __attribute__((ext_vector_type(4))) float    f32x4;

#define BAR() do { \
    asm volatile("s_waitcnt lgkmcnt(0)" ::: "memory"); \
    __builtin_amdgcn_sched_barrier(0); \
    __builtin_amdgcn_s_barrier(); \
    __builtin_amdgcn_sched_barrier(0); \
} while (0)

__device__ __forceinline__ unsigned short f2h(float x) {
    union { _Float16 h; unsigned short s; } u;
    u.h = (_Float16)x;
    return u.s;
}

// Pre-scaled 8-trans cell update (= R16..R19).
__device__ __forceinline__ float cell_upd(f32x4 g, float& cst) {
    const float K2 = 2.8853900817779268f;
    float eg  = __builtin_amdgcn_exp2f(fminf(fmaxf(g[2], -126.0f), 126.0f));
    float ei  = __builtin_amdgcn_exp2f(g[0]);
    float ef  = __builtin_amdgcn_exp2f(g[1]);
    float eo  = __builtin_amdgcn_exp2f(g[3]);
    float itg = (eg - 1.0f) * __builtin_amdgcn_rcpf((1.0f + ei) * (1.0f + eg));
    float fg  = __builtin_amdgcn_rcpf(1.0f + ef);
    float c   = fmaf(fg, cst, itg);
    cst = c;
    float ec  = __builtin_amdgcn_exp2f(fminf(fmaxf(K2 * c, -126.0f), 126.0f));
    return (ec - 1.0f) * __builtin_amdgcn_rcpf((1.0f + eo) * (1.0f + ec));
}

// Weights -> fp16 frags, pre-scaled per gate row ((gp&3)==2 -> +K2 else -K1).
template<bool L0M, int NT, int KS>
__device__ __forceinline__ void load_wb(int T0, int lane,
    const float* __restrict__ w_ih, const float* __restrict__ w_hh,
    const float* __restrict__ b_ih, const float* __restrict__ b_hh,
    half8 (&W)[NT][KS])
{
    const float K1 = 1.4426950408889634f, K2 = 2.8853900817779268f;
    const int m = lane & 15, kg = lane >> 4;
    #pragma unroll
    for (int q = 0; q < NT; ++q) {
        int gp = (T0 + q) * 16 + m;
        int gr = (gp < 200) ? ((gp & 3) * 50 + (gp >> 2)) : -1;
        float scale = ((gp & 3) == 2) ? K2 : -K1;
        #pragma unroll
        for (int ks = 0; ks < KS; ++ks)
            #pragma unroll
            for (int e = 0; e < 8; ++e) {
                int k = ks * 32 + kg * 8 + e;
                float v = 0.0f;
                if (gr >= 0) {
                    if (L0M) {
                        if (k < 8) v = w_ih[gr * 8 + k];
                        else if (k < 58) v = w_hh[gr * 50 + (k - 8)];
                        else if (k == 58) v = b_ih[gr] + b_hh[gr];
                    } else {
                        if (k < 50) v = w_ih[gr * 50 + k];
                        else if (k == 50) v = b_ih[gr] + b_hh[gr];
                        else if (k >= 64 && k < 114) v = w_hh[gr * 50 + (k - 64)];
                    }
                }
                W[q][ks][e] = (_Float16)(v * scale);
            }
    }
}

// ---- L0 wave ----
template<int T0, int NT, bool XST>
__device__ void role_l0(int lane, int b0, const float* __restrict__ xf,
    const float* w_ih, const float* w_hh, const float* b_ih, const float* b_hh,
    short (*H0)[BUFR])
{
    half8 W[NT][2];
    load_wb<true, NT, 2>(T0, lane, w_ih, w_hh, b_ih, b_hh, W);
    float cst[NT];
    #pragma unroll
    for (int q = 0; q < NT; ++q) cst[q] = 0.0f;
    const int b = lane & 15, kg = lane >> 4;
    const int o0 = kg * GS + b * 8;
    const int o4 = (4 + kg) * GS + b * 8;
    int wof[NT];
    #pragma unroll
    for (int q = 0; q < NT; ++q) {
        int n = (T0 + q) * 4 + kg;
        wof[q] = (1 + (n >> 3)) * GS + b * 8 + (n & 7);
    }

    for (int ii = 0; ii < NGRP; ++ii) {
        #pragma unroll
        for (int p = 0; p < 6; ++p) {
            const int it = ii * 6 + p;
            const bool stg = XST && (kg == 0) && (it + 1 < T_STEPS);
            float4 xa, xb2;
            if (stg) {
                const float* xr = &xf[((size_t)(b0 + b) * T_STEPS + (it + 1)) * 8];
                xa  = *(const float4*)xr;
                xb2 = *(const float4*)(xr + 4);
            }
            if (it < T_STEPS) {
                const short* rb = H0[p & 1];
                short*       wb = H0[(p + 1) & 1];
                half8 A0 = *(const half8*)&rb[o0];
                half8 A1 = *(const half8*)&rb[o4];
                f32x4 accA[NT], accB[NT];
                #pragma unroll
                for (int q = 0; q < NT; ++q) {
                    accA[q] = (f32x4){0.0f, 0.0f, 0.0f, 0.0f};
                    accB[q] = (f32x4){0.0f, 0.0f, 0.0f, 0.0f};
                }
                #pragma unroll
                for (int q = 0; q < NT; ++q)
                    accA[q] = __builtin_amdgcn_mfma_f32_16x16x32_f16(W[q][0], A0, accA[q], 0, 0, 0);
                #pragma unroll
                for (int q = 0; q < NT; ++q)
                    accB[q] = __builtin_amdgcn_mfma_f32_16x16x32_f16(W[q][1], A1, accB[q], 0, 0, 0);
                #pragma unroll
                for (int q = 0; q < NT; ++q) {
                    int n = (T0 + q) * 4 + kg;
                    if (n < 50) {
                        float h = cell_upd(accA[q] + accB[q], cst[q]);
                        wb[wof[q]] = (short)f2h(h);
                    }
                }
            }
            if (stg) {
                short hi[8];
                hi[0] = (short)f2h(xa.x);  hi[1] = (short)f2h(xa.y);
                hi[2] = (short)f2h(xa.z);  hi[3] = (short)f2h(xa.w);
                hi[4] = (short)f2h(xb2.x); hi[5] = (short)f2h(xb2.y);
                hi[6] = (short)f2h(xb2.z); hi[7] = (short)f2h(xb2.w);
                *(half8*)&H0[(p + 1) & 1][b * 8] = *(half8*)hi;
            }
            BAR();
        }
    }
}

// ---- Mid wave ----
template<int T0, int NT, bool LASTL>
__device__ void role_mid(int lane,
    const float* w_ih, const float* w_hh, const float* b_ih, const float* b_hh,
    short (*H0)[BUFR], short (*H1)[BUFR], short (*H2)[BUFR], float* hfp)
{
    constexpr int SKEW = LASTL ? 2 : 1;
    half8 W[NT][4];
    load_wb<false, NT, 4>(T0, lane, w_ih, w_hh, b_ih, b_hh, W);
    float cst[NT];
    #pragma unroll
    for (int q = 0; q < NT; ++q) cst[q] = 0.0f;
    const int b = lane & 15, kg = lane >> 4;
    const int o1 = (1 + kg) * GS + b * 8;
    const int o5 = (5 + kg) * GS + b * 8;
    int wof[NT];
    #pragma unroll
    for (int q = 0; q < NT; ++q) {
        int n = (T0 + q) * 4 + kg;
        wof[q] = (1 + (n >> 3)) * GS + b * 8 + (n & 7);
    }

    for (int ii = 0; ii < NGRP; ++ii) {
        #pragma unroll
        for (int p = 0; p < 6; ++p) {
            const int it = ii * 6 + p;
            const int t = it - SKEW;
            if ((unsigned)t < T_STEPS) {
                const short* xsb = LASTL ? H1[(p + 1) % 3] : H0[p & 1];
                const short* hsb = LASTL ? H2[(p + 1) & 1] : H1[(p + 1) % 3];
                short*       wb  = LASTL ? H2[p & 1]       : H1[(p + 2) % 3];

                half8 Ap0 = *(const half8*)&xsb[o1];
                half8 Ap1 = *(const half8*)&xsb[o5];
                half8 Ap2 = *(const half8*)&hsb[o1];
                half8 Ap3 = *(const half8*)&hsb[o5];

                f32x4 accA[NT], accB[NT];
                #pragma unroll
                for (int q = 0; q < NT; ++q) {
                    accA[q] = (f32x4){0.0f, 0.0f, 0.0f, 0.0f};
                    accB[q] = (f32x4){0.0f, 0.0f, 0.0f, 0.0f};
                }
                #pragma unroll
                for (int q = 0; q < NT; ++q)
                    accA[q] = __builtin_amdgcn_mfma_f32_16x16x32_f16(W[q][0], Ap0, accA[q], 0, 0, 0);
                #pragma unroll
                for (int q = 0; q < NT; ++q)
                    accB[q] = __builtin_amdgcn_mfma_f32_16x16x32_f16(W[q][1], Ap1, accB[q], 0, 0, 0);
                #pragma unroll
                for (int q = 0; q < NT; ++q)
                    accA[q] = __builtin_amdgcn_mfma_f32_16x16x32_f16(W[q][2], Ap2, accA[q], 0, 0, 0);
                #pragma unroll
                for (int q = 0; q < NT; ++q)
                    accB[q] = __builtin_amdgcn_mfma_f32_16x16x32_f16(W[q][3], Ap3, accB[q], 0, 0, 0);

                #pragma unroll
                for (int q = 0; q < NT; ++q) {
                    int n = (T0 + q) * 4 + kg;
                    if (n < 50) {
                        float h = cell_upd(accA[q] + accB[q], cst[q]);
                        wb[wof[q]] = (short)f2h(h);
                        if (LASTL && t == T_STEPS - 1) hfp[b * 56 + n] = h;
                    }
                }
            }
            BAR();
        }
    }
}

__global__ __launch_bounds__(NTHR) void lstm_fused(
    const float* __restrict__ xf,
    const float* w_ih0, const float* w_hh0, const float* b_ih0, const float* b_hh0,
    const float* w_ih1, const float* w_hh1, const float* b_ih1, const float* b_hh1,
    const float* w_ih2, const float* w_hh2, const float* b_ih2, const float* b_hh2,
    const float* __restrict__ w_fc, const float* __restrict__ b_fc,
    float* __restrict__ out)
{
    __shared__ __align__(16) short H0[2][BUFR];
    __shared__ __align__(16) short H1[3][BUFR];
    __shared__ __align__(16) short H2[2][BUFR];
    __shared__ __align__(16) float hf[16 * 56];

    const int tid  = threadIdx.x;
    const int lane = tid & 63;
    const int wid  = tid >> 6;
    const int b0   = blockIdx.x * 16;

    for (int i = tid; i < 2 * BUFR; i += NTHR) { ((short*)H0)[i] = 0; ((short*)H2)[i] = 0; }
    for (int i = tid; i < 3 * BUFR; i += NTHR) ((short*)H1)[i] = 0;
    __syncthreads();

    if (tid < 80) {
        int bufi = tid >> 4, b = tid & 15;
        short* bp = (bufi < 2) ? H0[bufi] : H1[bufi - 2];
        bp[7 * GS + b * 8 + 2] = (short)0x3C00;
    }
    if (tid < 16) {
        int b = tid;
        #pragma unroll
        for (int j = 0; j < 8; ++j) {
            float v = xf[((size_t)(b0 + b) * T_STEPS + 0) * 8 + j];
            H0[0][b * 8 + j] = (short)f2h(v);
        }
    }
    __syncthreads();

    if      (wid == 0)  role_l0<0,  4, false>(lane, b0, xf, w_ih0, w_hh0, b_ih0, b_hh0, H0);
    else if (wid == 1)  role_l0<4,  3, false>(lane, b0, xf, w_ih0, w_hh0, b_ih0, b_hh0, H0);
    else if (wid == 2)  role_l0<7,  3, false>(lane, b0, xf, w_ih0, w_hh0, b_ih0, b_hh0, H0);
    else if (wid == 3)  role_l0<10, 3, true >(lane, b0, xf, w_ih0, w_hh0, b_ih0, b_hh0, H0);
    else if (wid == 4)  role_mid<0,  3, false>(lane, w_ih1, w_hh1, b_ih1, b_hh1, H0, H1, H2, nullptr);
    else if (wid == 5)  role_mid<3,  2, false>(lane, w_ih1, w_hh1, b_ih1, b_hh1, H0, H1, H2, nullptr);
    else if (wid == 6)  role_mid<5,  2, false>(lane, w_ih1, w_hh1, b_ih1, b_hh1, H0, H1, H2, nullptr);
    else if (wid == 7)  role_mid<7,  2, false>(lane, w_ih1, w_hh1, b_ih1, b_hh1, H0, H1, H2, nullptr);
    else if (wid == 8)  role_mid<9,  2, false>(lane, w_ih1, w_hh1, b_ih1, b_hh1, H0, H1, H2, nullptr);
    else if (wid == 9)  role_mid<11, 2, false>(lane, w_ih1, w_hh1, b_ih1, b_hh1, H0, H1, H2, nullptr);
    else if (wid == 10) role_mid<0,  3, true >(lane, w_ih2, w_hh2, b_ih2, b_hh2, H0, H1, H2, hf);
    else if (wid == 11) role_mid<3,  2, true >(lane, w_ih2, w_hh2, b_ih2, b_hh2, H0, H1, H2, hf);
    else if (wid == 12) role_mid<5,  2, true >(lane, w_ih2, w_hh2, b_ih2, b_hh2, H0, H1, H2, hf);
    else if (wid == 13) role_mid<7,  2, true >(lane, w_ih2, w_hh2, b_ih2, b_hh2, H0, H1, H2, hf);
    else if (wid == 14) role_mid<9,  2, true >(lane, w_ih2, w_hh2, b_ih2, b_hh2, H0, H1, H2, hf);
    else                role_mid<11, 2, true >(lane, w_ih2, w_hh2, b_ih2, b_hh2, H0, H1, H2, hf);

    __syncthreads();

    if (tid < 96) {
        int b = tid / 6, o = tid - b * 6;
        float a = b_fc[o];
        #pragma unroll
        for (int u = 0; u < 50; ++u)
            a = fmaf(w_fc[o * 50 + u], hf[b * 56 + u], a);
        out[(size_t)(b0 + b) * 6 + o] = a;
    }
}

extern "C" void kernel_launch(void* const* d_in, const int* in_sizes, int n_in,
                              void* d_out, int out_size, void* d_ws, size_t ws_size,
                              hipStream_t stream) {
    (void)in_sizes; (void)n_in; (void)d_ws; (void)ws_size; (void)out_size;

    const float* x     = (const float*)d_in[0];
    const float* w_ih0 = (const float*)d_in[1];
    const float* w_hh0 = (const float*)d_in[2];
    const float* b_ih0 = (const float*)d_in[3];
    const float* b_hh0 = (const float*)d_in[4];
    const float* w_ih1 = (const float*)d_in[5];
    const float* w_hh1 = (const float*)d_in[6];
    const float* b_ih1 = (const float*)d_in[7];
    const float* b_hh1 = (const float*)d_in[8];
    const float* w_ih2 = (const float*)d_in[9];
    const float* w_hh2 = (const float*)d_in[10];
    const float* b_ih2 = (const float*)d_in[11];
    const float* b_hh2 = (const float*)d_in[12];
    const float* w_fc  = (const float*)d_in[13];
    const float* b_fc  = (const float*)d_in[14];
    float* out = (float*)d_out;

    lstm_fused<<<dim3(BTOT / 16), dim3(NTHR), 0, stream>>>(
        x, w_ih0, w_hh0, b_ih0, b_hh0, w_ih1, w_hh1, b_ih1, b_hh1,
        w_ih2, w_hh2, b_ih2, b_hh2, w_fc, b_fc, out);
}